// Round 3
// baseline (405.198 us; speedup 1.0000x reference)
//
#include <hip/hip_runtime.h>
#include <hip/hip_bf16.h>

#define B_SZ 16
#define C_IN 256
#define N_SP 2304
#define K_INT 128
#define NTILE 36  // q-tiles of 64
#define MT 32     // key/value m-tile
#define MITER 72  // N_SP / MT

typedef __attribute__((ext_vector_type(8))) short short8;
typedef __attribute__((ext_vector_type(4))) float f32x4;

// bf16 weights, converted once by wcvt_kernel: [p][k][c], p=0 theta, p=1 phi
__device__ __align__(16) short g_Wbf[2 * K_INT * C_IN];

// packed fp32x2 -> bf16x2 (v_cvt_pk_bf16_f32, RNE)
__device__ inline unsigned pk_bf16(float a, float b) {
  float2 f; f.x = a; f.y = b;
  __hip_bfloat162 h = __float22bfloat162_rn(f);
  unsigned u;
  __builtin_memcpy(&u, &h, sizeof(u));
  return u;
}

// ---------------------------------------------------------------------------
// One-time weight convert: f32 -> bf16 into g_Wbf (128 KiB, L2-resident).
// ---------------------------------------------------------------------------
__global__ __launch_bounds__(256) void wcvt_kernel(
    const float* __restrict__ tw, const float* __restrict__ pw)
{
  const int i = (blockIdx.x * 256 + threadIdx.x) * 4;  // grid 32 covers 32768
  float4 a = *(const float4*)(tw + i);
  float4 p = *(const float4*)(pw + i);
  uint2 ua; ua.x = pk_bf16(a.x, a.y); ua.y = pk_bf16(a.z, a.w);
  uint2 up; up.x = pk_bf16(p.x, p.y); up.y = pk_bf16(p.z, p.w);
  *(uint2*)(g_Wbf + i) = ua;
  *(uint2*)(g_Wbf + 32768 + i) = up;
}

// ---------------------------------------------------------------------------
// Projection: Qt[b][n][k], Kt[b][n][k] (bf16), Gbf[b][c][n] = bf16(x).
// (unchanged this round -- its counters surface once attn < proj)
// ---------------------------------------------------------------------------
__global__ __launch_bounds__(256) void proj_kernel(
    const float* __restrict__ x,
    const float* __restrict__ theta_b, const float* __restrict__ phi_b,
    short* __restrict__ Qt, short* __restrict__ Kt, short* __restrict__ Gbf)
{
  __shared__ short Xl[64][264];  // [n][c], +8 pad

  const int b  = blockIdx.x / NTILE;
  const int n0 = (blockIdx.x % NTILE) * 64;
  const int t  = threadIdx.x;  // t == channel c for staging

  // ---- stage: read x row (64 fp32), packed-convert, write Gbf + LDS T ----
  {
    const float* xrow = x + ((size_t)b * C_IN + t) * N_SP + n0;
    unsigned tp[32];
#pragma unroll
    for (int i = 0; i < 16; ++i) {
      float4 v = ((const float4*)xrow)[i];
      tp[2*i]   = pk_bf16(v.x, v.y);
      tp[2*i+1] = pk_bf16(v.z, v.w);
    }
    uint4* grow = (uint4*)(Gbf + ((size_t)b * C_IN + t) * N_SP + n0);
#pragma unroll
    for (int i = 0; i < 8; ++i) {
      uint4 u; u.x = tp[4*i]; u.y = tp[4*i+1]; u.z = tp[4*i+2]; u.w = tp[4*i+3];
      grow[i] = u;
    }
#pragma unroll
    for (int j = 0; j < 32; ++j) {
      Xl[2*j][t]   = (short)tp[j];
      Xl[2*j+1][t] = (short)(tp[j] >> 16);
    }
  }
  __syncthreads();

  const int wave = t >> 6, lane = t & 63;
  const int col = lane & 15, quad = lane >> 4;

  f32x4 acc[2][2][4];
#pragma unroll
  for (int p = 0; p < 2; ++p)
#pragma unroll
    for (int kr = 0; kr < 2; ++kr)
#pragma unroll
      for (int j = 0; j < 4; ++j) {
        acc[p][kr][j][0] = 0.f; acc[p][kr][j][1] = 0.f;
        acc[p][kr][j][2] = 0.f; acc[p][kr][j][3] = 0.f;
      }

#pragma unroll
  for (int cs = 0; cs < 8; ++cs) {
    const int c0 = cs * 32;
    short8 afr[2][2];
#pragma unroll
    for (int p = 0; p < 2; ++p)
#pragma unroll
      for (int kr = 0; kr < 2; ++kr) {
        const int k = wave * 32 + kr * 16 + col;
        afr[p][kr] = *(const short8*)(g_Wbf + p * 32768 + k * C_IN + c0 + quad * 8);
      }
#pragma unroll
    for (int j = 0; j < 4; ++j) {
      short8 bfr = *(const short8*)&Xl[j * 16 + col][c0 + quad * 8];
#pragma unroll
      for (int p = 0; p < 2; ++p)
#pragma unroll
        for (int kr = 0; kr < 2; ++kr)
          acc[p][kr][j] = __builtin_amdgcn_mfma_f32_16x16x32_bf16(
              afr[p][kr], bfr, acc[p][kr][j], 0, 0, 0);
    }
  }

  // ---- epilogue: bias + transpose-store to [b][n][k] bf16 ----
#pragma unroll
  for (int p = 0; p < 2; ++p) {
    const float* bias = p ? phi_b : theta_b;
    short* dst = p ? Kt : Qt;
#pragma unroll
    for (int kr = 0; kr < 2; ++kr) {
      const int k0 = wave * 32 + kr * 16 + quad * 4;
      float4 bv = *(const float4*)(bias + k0);
#pragma unroll
      for (int j = 0; j < 4; ++j) {
        const int n = n0 + j * 16 + col;
        f32x4 v = acc[p][kr][j];
        uint2 sv;
        sv.x = pk_bf16(v[0] + bv.x, v[1] + bv.y);
        sv.y = pk_bf16(v[2] + bv.z, v[3] + bv.w);
        *(uint2*)(dst + ((size_t)b * N_SP + n) * K_INT + k0) = sv;
      }
    }
  }
}

// ---------------------------------------------------------------------------
// Flash attention, m-tile 32, NO K/G LDS staging:
//  - QK A-fragments and PV B-fragments are DIRECT b128 global loads
//    (Kt[n][k] and Gbf[c][n] layouts make fragments contiguous); K/G are
//    L2-resident per-b (590KB / 1.18MB) -- staging them was pure overhead
//  - P exchange via lane-linear blob: producer writes blob[wave][lane],
//    consumer reads blob[qt][lane] (A-fragment lane-mapping identical on
//    both sides) -> canonical linear pattern, zero bank conflicts, no swizzle
//  - double-buffered P -> ONE barrier per iter
//  - K prefetched one iter ahead (issued post-barrier); G issued post-QK
//  - LDS: 8.4KB total; DS ops/wave/iter: 23 -> 5
// ---------------------------------------------------------------------------
__global__ __launch_bounds__(256) void attn_kernel(
    const short* __restrict__ Qt, const short* __restrict__ Kt,
    const short* __restrict__ Gbf, float* __restrict__ out)
{
  __shared__ __align__(16) short Pblob[2][4][64][8];  // [par][wave][lane][8] = 8KB
  __shared__ float l_lds[64];

  const int b   = blockIdx.x / NTILE;
  const int qn0 = (blockIdx.x % NTILE) * 64;
  const int t = threadIdx.x;
  const int wave = t >> 6, lane = t & 63;
  const int col = lane & 15, quad = lane >> 4;

  const short* Ktb = Kt  + (size_t)b * N_SP * K_INT;
  const short* Gb  = Gbf + (size_t)b * C_IN * N_SP;

  // Q fragments in registers for the whole loop (B-operand layout: col=q)
  short8 qf[4];
  {
    const short* qb = Qt + ((size_t)b * N_SP + qn0 + wave * 16 + col) * K_INT + quad * 8;
#pragma unroll
    for (int kk = 0; kk < 4; ++kk) qf[kk] = *(const short8*)(qb + kk * 32);
  }

  f32x4 yacc[4][4];  // [q-tile][c-tile]
#pragma unroll
  for (int i = 0; i < 4; ++i)
#pragma unroll
    for (int j = 0; j < 4; ++j) {
      yacc[i][j][0] = 0.f; yacc[i][j][1] = 0.f;
      yacc[i][j][2] = 0.f; yacc[i][j][3] = 0.f;
    }
  f32x4 lacc;
  lacc[0] = 0.f; lacc[1] = 0.f; lacc[2] = 0.f; lacc[3] = 0.f;

  short8 ones;
#pragma unroll
  for (int j = 0; j < 8; ++j) ones[j] = (short)0x3F80;  // bf16 1.0

  const float SC2 = 0.12754859f;  // (1/sqrt(128)) * log2(e)

  // per-lane operand base pointers (fragments are contiguous 16B)
  const short* kptr = Ktb + col * K_INT + quad * 8;                   // K rows m0+col
  const short* gptr = Gb + ((size_t)(wave * 64 + col)) * N_SP + quad * 8;  // G rows c

  // preload K fragments for mt=0
  short8 kf[8];
#pragma unroll
  for (int kk = 0; kk < 4; ++kk) {
    kf[2 * kk]     = *(const short8*)(kptr + kk * 32);
    kf[2 * kk + 1] = *(const short8*)(kptr + 2048 + kk * 32);
  }

  for (int mt = 0; mt < MITER; ++mt) {
    // ---- S = Q K^T (swapped: A=K, rows m0..m0+31; cols = q) ----
    f32x4 s0, s1;
    s0[0] = 0.f; s0[1] = 0.f; s0[2] = 0.f; s0[3] = 0.f;
    s1[0] = 0.f; s1[1] = 0.f; s1[2] = 0.f; s1[3] = 0.f;
#pragma unroll
    for (int kk = 0; kk < 4; ++kk) {
      s0 = __builtin_amdgcn_mfma_f32_16x16x32_bf16(kf[2 * kk],     qf[kk], s0, 0, 0, 0);
      s1 = __builtin_amdgcn_mfma_f32_16x16x32_bf16(kf[2 * kk + 1], qf[kk], s1, 0, 0, 0);
    }

    // ---- G fragments for this iter (consumed after the barrier) ----
    short8 gb[4];
#pragma unroll
    for (int ct = 0; ct < 4; ++ct)
      gb[ct] = *(const short8*)(gptr + (size_t)ct * 16 * N_SP + mt * 32);

    // ---- softmax-lite + in-register transpose to A-fragment ----
    unsigned u0 = pk_bf16(exp2f(s0[0] * SC2), exp2f(s0[1] * SC2));
    unsigned u1 = pk_bf16(exp2f(s0[2] * SC2), exp2f(s0[3] * SC2));
    unsigned u2 = pk_bf16(exp2f(s1[0] * SC2), exp2f(s1[1] * SC2));
    unsigned u3 = pk_bf16(exp2f(s1[2] * SC2), exp2f(s1[3] * SC2));
    asm("v_permlane32_swap_b32 %0, %1" : "+v"(u0), "+v"(u2));
    asm("v_permlane32_swap_b32 %0, %1" : "+v"(u1), "+v"(u3));
    asm("v_permlane16_swap_b32 %0, %1" : "+v"(u0), "+v"(u2));
    asm("v_permlane16_swap_b32 %0, %1" : "+v"(u1), "+v"(u3));
    unsigned uu[4] = {u0, u1, u2, u3};
    short8 pa; __builtin_memcpy(&pa, uu, 16);

    lacc = __builtin_amdgcn_mfma_f32_16x16x32_bf16(pa, ones, lacc, 0, 0, 0);

    // ---- P exchange: lane-linear write, one barrier, lane-linear reads ----
    *(short8*)&Pblob[mt & 1][wave][lane][0] = pa;
    __syncthreads();

    // ---- prefetch K fragments for next iter (consumed next QK) ----
    if (mt + 1 < MITER) {
      const short* kp = kptr + (size_t)(mt + 1) * 4096;
#pragma unroll
      for (int kk = 0; kk < 4; ++kk) {
        kf[2 * kk]     = *(const short8*)(kp + kk * 32);
        kf[2 * kk + 1] = *(const short8*)(kp + 2048 + kk * 32);
      }
    }

    // ---- PV: Y[q][c] += P[q][m] G^T[m][c] ----
#pragma unroll
    for (int qt = 0; qt < 4; ++qt) {
      short8 paq = *(const short8*)&Pblob[mt & 1][qt][lane][0];
#pragma unroll
      for (int ct = 0; ct < 4; ++ct)
        yacc[qt][ct] = __builtin_amdgcn_mfma_f32_16x16x32_bf16(
            paq, gb[ct], yacc[qt][ct], 0, 0, 0);
    }
  }

  // ---- l exchange: wave w holds l[16w + quad*4 + r] in lacc[r] ----
  if (col == 0) {
#pragma unroll
    for (int r = 0; r < 4; ++r) l_lds[wave * 16 + quad * 4 + r] = lacc[r];
  }
  __syncthreads();

  // ---- epilogue: normalize and store out[b][c][n]; c = wave*64+ct*16+col ----
#pragma unroll
  for (int qt = 0; qt < 4; ++qt) {
    float4 lq = *(const float4*)&l_lds[qt * 16 + quad * 4];
    float4 iv;
    iv.x = 1.0f / lq.x; iv.y = 1.0f / lq.y; iv.z = 1.0f / lq.z; iv.w = 1.0f / lq.w;
    const int nb = qn0 + qt * 16 + quad * 4;
#pragma unroll
    for (int ct = 0; ct < 4; ++ct) {
      const int c = wave * 64 + ct * 16 + col;
      f32x4 v = yacc[qt][ct];
      float4 o;
      o.x = v[0] * iv.x; o.y = v[1] * iv.y; o.z = v[2] * iv.z; o.w = v[3] * iv.w;
      *(float4*)(out + ((size_t)b * C_IN + c) * N_SP + nb) = o;
    }
  }
}

extern "C" void kernel_launch(void* const* d_in, const int* in_sizes, int n_in,
                              void* d_out, int out_size, void* d_ws, size_t ws_size,
                              hipStream_t stream) {
  const float* x  = (const float*)d_in[0];
  const float* tw = (const float*)d_in[1];
  const float* tb = (const float*)d_in[2];
  const float* pw = (const float*)d_in[3];
  const float* pb = (const float*)d_in[4];
  float* out = (float*)d_out;

  // workspace: Qt (9.4MB) | Kt (9.4MB) | Gbf (18.9MB) = 37.75 MB total
  short* Qt  = (short*)d_ws;
  short* Kt  = Qt + (size_t)B_SZ * N_SP * K_INT;
  short* Gbf = Kt + (size_t)B_SZ * N_SP * K_INT;

  wcvt_kernel<<<32, 256, 0, stream>>>(tw, pw);
  proj_kernel<<<B_SZ * NTILE, 256, 0, stream>>>(x, tb, pb, Qt, Kt, Gbf);
  attn_kernel<<<B_SZ * NTILE, 256, 0, stream>>>(Qt, Kt, Gbf, out);
}

// Round 4
// 245.283 us; speedup vs baseline: 1.6520x; 1.6520x over previous
//
#include <hip/hip_runtime.h>
#include <hip/hip_bf16.h>

#define B_SZ 16
#define C_IN 256
#define N_SP 2304
#define K_INT 128
#define NTILE 36  // q-tiles of 64
#define MT 32     // key/value m-tile
#define MITER 72  // N_SP / MT

typedef __attribute__((ext_vector_type(8))) short short8;
typedef __attribute__((ext_vector_type(4))) float f32x4;

// bf16 weights, converted once by wcvt_kernel: [p][k][c], p=0 theta, p=1 phi
__device__ __align__(16) short g_Wbf[2 * K_INT * C_IN];

// packed fp32x2 -> bf16x2 (v_cvt_pk_bf16_f32, RNE)
__device__ inline unsigned pk_bf16(float a, float b) {
  float2 f; f.x = a; f.y = b;
  __hip_bfloat162 h = __float22bfloat162_rn(f);
  unsigned u;
  __builtin_memcpy(&u, &h, sizeof(u));
  return u;
}

// ---------------------------------------------------------------------------
// One-time weight convert: f32 -> bf16 into g_Wbf (128 KiB, L2-resident).
// ---------------------------------------------------------------------------
__global__ __launch_bounds__(256) void wcvt_kernel(
    const float* __restrict__ tw, const float* __restrict__ pw)
{
  const int i = (blockIdx.x * 256 + threadIdx.x) * 4;  // grid 32 covers 32768
  float4 a = *(const float4*)(tw + i);
  float4 p = *(const float4*)(pw + i);
  uint2 ua; ua.x = pk_bf16(a.x, a.y); ua.y = pk_bf16(a.z, a.w);
  uint2 up; up.x = pk_bf16(p.x, p.y); up.y = pk_bf16(p.z, p.w);
  *(uint2*)(g_Wbf + i) = ua;
  *(uint2*)(g_Wbf + 32768 + i) = up;
}

// ---------------------------------------------------------------------------
// Projection: Qt[b][n][k], Kt[b][n][k] (bf16), Gbf[b][c][n] = bf16(x).
// (unchanged this round)
// ---------------------------------------------------------------------------
__global__ __launch_bounds__(256) void proj_kernel(
    const float* __restrict__ x,
    const float* __restrict__ theta_b, const float* __restrict__ phi_b,
    short* __restrict__ Qt, short* __restrict__ Kt, short* __restrict__ Gbf)
{
  __shared__ short Xl[64][264];  // [n][c], +8 pad

  const int b  = blockIdx.x / NTILE;
  const int n0 = (blockIdx.x % NTILE) * 64;
  const int t  = threadIdx.x;  // t == channel c for staging

  // ---- stage: read x row (64 fp32), packed-convert, write Gbf + LDS T ----
  {
    const float* xrow = x + ((size_t)b * C_IN + t) * N_SP + n0;
    unsigned tp[32];
#pragma unroll
    for (int i = 0; i < 16; ++i) {
      float4 v = ((const float4*)xrow)[i];
      tp[2*i]   = pk_bf16(v.x, v.y);
      tp[2*i+1] = pk_bf16(v.z, v.w);
    }
    uint4* grow = (uint4*)(Gbf + ((size_t)b * C_IN + t) * N_SP + n0);
#pragma unroll
    for (int i = 0; i < 8; ++i) {
      uint4 u; u.x = tp[4*i]; u.y = tp[4*i+1]; u.z = tp[4*i+2]; u.w = tp[4*i+3];
      grow[i] = u;
    }
#pragma unroll
    for (int j = 0; j < 32; ++j) {
      Xl[2*j][t]   = (short)tp[j];
      Xl[2*j+1][t] = (short)(tp[j] >> 16);
    }
  }
  __syncthreads();

  const int wave = t >> 6, lane = t & 63;
  const int col = lane & 15, quad = lane >> 4;

  f32x4 acc[2][2][4];
#pragma unroll
  for (int p = 0; p < 2; ++p)
#pragma unroll
    for (int kr = 0; kr < 2; ++kr)
#pragma unroll
      for (int j = 0; j < 4; ++j) {
        acc[p][kr][j][0] = 0.f; acc[p][kr][j][1] = 0.f;
        acc[p][kr][j][2] = 0.f; acc[p][kr][j][3] = 0.f;
      }

#pragma unroll
  for (int cs = 0; cs < 8; ++cs) {
    const int c0 = cs * 32;
    short8 afr[2][2];
#pragma unroll
    for (int p = 0; p < 2; ++p)
#pragma unroll
      for (int kr = 0; kr < 2; ++kr) {
        const int k = wave * 32 + kr * 16 + col;
        afr[p][kr] = *(const short8*)(g_Wbf + p * 32768 + k * C_IN + c0 + quad * 8);
      }
#pragma unroll
    for (int j = 0; j < 4; ++j) {
      short8 bfr = *(const short8*)&Xl[j * 16 + col][c0 + quad * 8];
#pragma unroll
      for (int p = 0; p < 2; ++p)
#pragma unroll
        for (int kr = 0; kr < 2; ++kr)
          acc[p][kr][j] = __builtin_amdgcn_mfma_f32_16x16x32_bf16(
              afr[p][kr], bfr, acc[p][kr][j], 0, 0, 0);
    }
  }

  // ---- epilogue: bias + transpose-store to [b][n][k] bf16 ----
#pragma unroll
  for (int p = 0; p < 2; ++p) {
    const float* bias = p ? phi_b : theta_b;
    short* dst = p ? Kt : Qt;
#pragma unroll
    for (int kr = 0; kr < 2; ++kr) {
      const int k0 = wave * 32 + kr * 16 + quad * 4;
      float4 bv = *(const float4*)(bias + k0);
#pragma unroll
      for (int j = 0; j < 4; ++j) {
        const int n = n0 + j * 16 + col;
        f32x4 v = acc[p][kr][j];
        uint2 sv;
        sv.x = pk_bf16(v[0] + bv.x, v[1] + bv.y);
        sv.y = pk_bf16(v[2] + bv.z, v[3] + bv.w);
        *(uint2*)(dst + ((size_t)b * N_SP + n) * K_INT + k0) = sv;
      }
    }
  }
}

// ---------------------------------------------------------------------------
// Flash attention v4 (hybrid homes, 1 barrier/iter):
//  - K: LDS double-buffered, reg-prefetch 1 iter ahead (proven latency hiding);
//    swizzle chunk^(row&7): enumerated conflict-free on BOTH write and read
//    (R2's (row>>1)<<1 variant was read-side 2-way = the 1.19e7 counter)
//  - G: read once per block (c-split) -> NO LDS; direct global b128 into regs,
//    prefetched one FULL iteration ahead (fixes R3's ~200cy lead -> latency)
//  - P: lane-linear blob (measured 0-conflict in R3), double-buffered
//  - ONE barrier/iter: K write targets buf^1 pre-barrier / read post-barrier;
//    P reads pre-next-barrier vs rewrite post-next-barrier (double-buffered)
//  DS ops/wave/iter: 23 -> 15 (all conflict-free); LDS 53.7KB -> 24.8KB
// ---------------------------------------------------------------------------
__global__ __launch_bounds__(256) void attn_kernel(
    const short* __restrict__ Qt, const short* __restrict__ Kt,
    const short* __restrict__ Gbf, float* __restrict__ out)
{
  __shared__ __align__(16) char Kl[2][8192];          // [buf][32 m][128 k] swz
  __shared__ __align__(16) short Pblob[2][4][64][8];  // [buf][wave][lane][8]
  __shared__ float l_lds[64];

  const int b   = blockIdx.x / NTILE;
  const int qn0 = (blockIdx.x % NTILE) * 64;
  const int t = threadIdx.x;
  const int wave = t >> 6, lane = t & 63;
  const int col = lane & 15, quad = lane >> 4;

  const short* Ktb = Kt  + (size_t)b * N_SP * K_INT;
  const short* Gb  = Gbf + (size_t)b * C_IN * N_SP;

  // Q fragments in registers for the whole loop (B-operand layout: col=q)
  short8 qf[4];
  {
    const short* qb = Qt + ((size_t)b * N_SP + qn0 + wave * 16 + col) * K_INT + quad * 8;
#pragma unroll
    for (int kk = 0; kk < 4; ++kk) qf[kk] = *(const short8*)(qb + kk * 32);
  }

  f32x4 yacc[4][4];  // [q-tile][c-tile]
#pragma unroll
  for (int i = 0; i < 4; ++i)
#pragma unroll
    for (int j = 0; j < 4; ++j) {
      yacc[i][j][0] = 0.f; yacc[i][j][1] = 0.f;
      yacc[i][j][2] = 0.f; yacc[i][j][3] = 0.f;
    }
  f32x4 lacc;
  lacc[0] = 0.f; lacc[1] = 0.f; lacc[2] = 0.f; lacc[3] = 0.f;

  short8 ones;
#pragma unroll
  for (int j = 0; j < 8; ++j) ones[j] = (short)0x3F80;  // bf16 1.0

  const float SC2 = 0.12754859f;  // (1/sqrt(128)) * log2(e)

  // ---- K LDS offsets: phys(r,chunk) = r*256 + ((chunk ^ (r&7))<<4) ----
  const int KW0 = (t >> 4) * 256 + ((((t & 15) ^ ((t >> 4) & 7))) << 4);  // +4096 row+16
  int KR0[4];
#pragma unroll
  for (int kk = 0; kk < 4; ++kk)
    KR0[kk] = col * 256 + ((((kk << 2) + quad) ^ (col & 7)) << 4);

  // ---- global offsets ----
  const int koff = (t >> 4) * K_INT + (t & 15) * 8;                       // K stage
  const short* gbase = Gb + ((size_t)(wave * 64 + col)) * N_SP + quad * 8; // G direct

  // ---- prologue: tile0 -> Kl[0]; kreg <- tile1; gA <- G tile0 ----
  short8 krA, krB;
  krA = *(const short8*)(Ktb + koff);
  krB = *(const short8*)(Ktb + 2048 + koff);
  *(short8*)(Kl[0] + KW0) = krA;
  *(short8*)(Kl[0] + KW0 + 4096) = krB;
  krA = *(const short8*)(Ktb + 4096 + koff);
  krB = *(const short8*)(Ktb + 6144 + koff);
  short8 gA[4], gB[4];
#pragma unroll
  for (int ct = 0; ct < 4; ++ct)
    gA[ct] = *(const short8*)(gbase + (size_t)ct * 16 * N_SP);
  __syncthreads();

#define SUBITER(MTV, CUR, GC, GN)                                              \
  {                                                                            \
    /* 1. QK: S = K(tile MTV) x Q  (A-frags from LDS) */                       \
    f32x4 s0, s1;                                                              \
    s0[0] = 0.f; s0[1] = 0.f; s0[2] = 0.f; s0[3] = 0.f;                        \
    s1[0] = 0.f; s1[1] = 0.f; s1[2] = 0.f; s1[3] = 0.f;                        \
    _Pragma("unroll")                                                          \
    for (int kk = 0; kk < 4; ++kk) {                                           \
      short8 a0 = *(const short8*)(Kl[CUR] + KR0[kk]);                         \
      s0 = __builtin_amdgcn_mfma_f32_16x16x32_bf16(a0, qf[kk], s0, 0, 0, 0);   \
      short8 a1 = *(const short8*)(Kl[CUR] + KR0[kk] + 4096);                  \
      s1 = __builtin_amdgcn_mfma_f32_16x16x32_bf16(a1, qf[kk], s1, 0, 0, 0);   \
    }                                                                          \
    /* 2. softmax-lite + in-register transpose to A-fragment */                \
    unsigned u0 = pk_bf16(exp2f(s0[0] * SC2), exp2f(s0[1] * SC2));             \
    unsigned u1 = pk_bf16(exp2f(s0[2] * SC2), exp2f(s0[3] * SC2));             \
    unsigned u2 = pk_bf16(exp2f(s1[0] * SC2), exp2f(s1[1] * SC2));             \
    unsigned u3 = pk_bf16(exp2f(s1[2] * SC2), exp2f(s1[3] * SC2));             \
    asm("v_permlane32_swap_b32 %0, %1" : "+v"(u0), "+v"(u2));                  \
    asm("v_permlane32_swap_b32 %0, %1" : "+v"(u1), "+v"(u3));                  \
    asm("v_permlane16_swap_b32 %0, %1" : "+v"(u0), "+v"(u2));                  \
    asm("v_permlane16_swap_b32 %0, %1" : "+v"(u1), "+v"(u3));                  \
    unsigned uu[4] = {u0, u1, u2, u3};                                         \
    short8 pa; __builtin_memcpy(&pa, uu, 16);                                  \
    lacc = __builtin_amdgcn_mfma_f32_16x16x32_bf16(pa, ones, lacc, 0, 0, 0);   \
    /* 3. P exchange write (lane-linear, conflict-free) */                     \
    *(short8*)&Pblob[CUR][wave][lane][0] = pa;                                 \
    /* 4. K stage write: tile MTV+1 -> Kl[CUR^1] (consumed next iter) */       \
    if ((MTV) + 1 < MITER) {                                                   \
      *(short8*)(Kl[(CUR) ^ 1] + KW0) = krA;                                   \
      *(short8*)(Kl[(CUR) ^ 1] + KW0 + 4096) = krB;                            \
    }                                                                          \
    /* 5. K global prefetch: tile MTV+2 (staged next iter) */                  \
    if ((MTV) + 2 < MITER) {                                                   \
      const short* kp = Ktb + (size_t)((MTV) + 2) * 4096 + koff;               \
      krA = *(const short8*)(kp);                                              \
      krB = *(const short8*)(kp + 2048);                                       \
    }                                                                          \
    /* 6. G global prefetch: tile MTV+1 (consumed next iter's PV) */           \
    if ((MTV) + 1 < MITER) {                                                   \
      _Pragma("unroll")                                                        \
      for (int ct = 0; ct < 4; ++ct)                                           \
        GN[ct] = *(const short8*)(gbase + (size_t)ct * 16 * N_SP +             \
                                  ((MTV) + 1) * 32);                           \
    }                                                                          \
    __syncthreads();                                                           \
    /* 8. PV: Y[q][c] += P[q][m] G^T[m][c]  (G from regs, P lane-linear) */    \
    _Pragma("unroll")                                                          \
    for (int qt = 0; qt < 4; ++qt) {                                           \
      short8 paq = *(const short8*)&Pblob[CUR][qt][lane][0];                   \
      _Pragma("unroll")                                                        \
      for (int ct = 0; ct < 4; ++ct)                                           \
        yacc[qt][ct] = __builtin_amdgcn_mfma_f32_16x16x32_bf16(                \
            paq, GC[ct], yacc[qt][ct], 0, 0, 0);                               \
    }                                                                          \
  }

  for (int mt2 = 0; mt2 < MITER / 2; ++mt2) {
    SUBITER(2 * mt2,     0, gA, gB)
    SUBITER(2 * mt2 + 1, 1, gB, gA)
  }
#undef SUBITER

  // ---- l exchange: wave w holds l[16w + quad*4 + r] in lacc[r] ----
  if (col == 0) {
#pragma unroll
    for (int r = 0; r < 4; ++r) l_lds[wave * 16 + quad * 4 + r] = lacc[r];
  }
  __syncthreads();

  // ---- epilogue: normalize and store out[b][c][n]; c = wave*64+ct*16+col ----
#pragma unroll
  for (int qt = 0; qt < 4; ++qt) {
    float4 lq = *(const float4*)&l_lds[qt * 16 + quad * 4];
    float4 iv;
    iv.x = 1.0f / lq.x; iv.y = 1.0f / lq.y; iv.z = 1.0f / lq.z; iv.w = 1.0f / lq.w;
    const int nb = qn0 + qt * 16 + quad * 4;
#pragma unroll
    for (int ct = 0; ct < 4; ++ct) {
      const int c = wave * 64 + ct * 16 + col;
      f32x4 v = yacc[qt][ct];
      float4 o;
      o.x = v[0] * iv.x; o.y = v[1] * iv.y; o.z = v[2] * iv.z; o.w = v[3] * iv.w;
      *(float4*)(out + ((size_t)b * C_IN + c) * N_SP + nb) = o;
    }
  }
}

extern "C" void kernel_launch(void* const* d_in, const int* in_sizes, int n_in,
                              void* d_out, int out_size, void* d_ws, size_t ws_size,
                              hipStream_t stream) {
  const float* x  = (const float*)d_in[0];
  const float* tw = (const float*)d_in[1];
  const float* tb = (const float*)d_in[2];
  const float* pw = (const float*)d_in[3];
  const float* pb = (const float*)d_in[4];
  float* out = (float*)d_out;

  // workspace: Qt (9.4MB) | Kt (9.4MB) | Gbf (18.9MB) = 37.75 MB total
  short* Qt  = (short*)d_ws;
  short* Kt  = Qt + (size_t)B_SZ * N_SP * K_INT;
  short* Gbf = Kt + (size_t)B_SZ * N_SP * K_INT;

  wcvt_kernel<<<32, 256, 0, stream>>>(tw, pw);
  proj_kernel<<<B_SZ * NTILE, 256, 0, stream>>>(x, tb, pb, Qt, Kt, Gbf);
  attn_kernel<<<B_SZ * NTILE, 256, 0, stream>>>(Qt, Kt, Gbf, out);
}